// Round 4
// baseline (1603.563 us; speedup 1.0000x reference)
//
#include <hip/hip_runtime.h>
#include <stdint.h>

// ---------------------------------------------------------------------------
// HiSA transformer block on MI355X (gfx950), bf16-MFMA implementation.
// B=2, S=2048, D=1024, H=16, dk=64, F=4096.
// R4: mask bit-packing fused into attention via wave-ballot (pack_mask_k
//     deleted); setprio around attn MFMA clusters.
// ---------------------------------------------------------------------------

typedef __attribute__((ext_vector_type(8))) short short8;     // 8 bf16 (4 VGPRs)
typedef __attribute__((ext_vector_type(4))) float f32x4;      // MFMA C/D frag
typedef __attribute__((ext_vector_type(4))) unsigned short u16x4;

__device__ __forceinline__ unsigned short f2bf(float f) {
    union { float f; unsigned u; } v; v.f = f;
    unsigned r = v.u + 0x7fffu + ((v.u >> 16) & 1u);   // round-to-nearest-even
    return (unsigned short)(r >> 16);
}

// async global->LDS, 16B per lane. LDS dest must be wave-uniform base + lane*16.
__device__ __forceinline__ void gload16(const void* gsrc, void* ldst) {
    __builtin_amdgcn_global_load_lds(
        (const __attribute__((address_space(1))) void*)gsrc,
        (__attribute__((address_space(3))) void*)ldst,
        16, 0, 0);
}

// st_16x32 XOR swizzle: toggle byte-bit5 with byte-bit9 (within 1KB subtile)
__device__ __forceinline__ int SWZ(int b) { return b ^ (((b >> 9) & 1) << 5); }

// ---------------------------------------------------------------------------
// f32 -> bf16 elementwise convert (vectorized)
// ---------------------------------------------------------------------------
__global__ __launch_bounds__(256) void f32_to_bf16_k(
    const float* __restrict__ in, unsigned short* __restrict__ out, int n4)
{
    int i = blockIdx.x * 256 + threadIdx.x;
    if (i < n4) {
        f32x4 v = *(const f32x4*)&in[(size_t)i * 4];
        u16x4 o = { f2bf(v[0]), f2bf(v[1]), f2bf(v[2]), f2bf(v[3]) };
        *(u16x4*)&out[(size_t)i * 4] = o;
    }
}

// ---------------------------------------------------------------------------
// W (K x N, f32) -> Wt (N x K, bf16) tiled transpose
// ---------------------------------------------------------------------------
__global__ __launch_bounds__(256) void transpose_k(
    const float* __restrict__ W, unsigned short* __restrict__ Wt, int K, int N)
{
    __shared__ float tile[32][33];
    const int n0 = blockIdx.x * 32, k0 = blockIdx.y * 32;
    const int tx = threadIdx.x & 31, ty = threadIdx.x >> 5;  // ty in [0,8)
#pragma unroll
    for (int i = 0; i < 32; i += 8)
        tile[ty + i][tx] = W[(size_t)(k0 + ty + i) * N + n0 + tx];
    __syncthreads();
#pragma unroll
    for (int i = 0; i < 32; i += 8)
        Wt[(size_t)(n0 + ty + i) * K + k0 + tx] = f2bf(tile[tx][ty + i]);
}

// ---------------------------------------------------------------------------
// per-head V^T: vt[(bh*64 + d)*2048 + s] = V[b, s, h, d]
// ---------------------------------------------------------------------------
__global__ __launch_bounds__(256) void vtrans_k(
    const unsigned short* __restrict__ qkv, unsigned short* __restrict__ vt)
{
    __shared__ unsigned short tile[32][34];
    const int s0 = blockIdx.x * 32;
    const int d0 = blockIdx.y * 32;
    const int bh = blockIdx.z, b = bh >> 4, h = bh & 15;
    const int tx = threadIdx.x & 31, ty = threadIdx.x >> 5;
#pragma unroll
    for (int i = 0; i < 32; i += 8)
        tile[ty + i][tx] = qkv[(size_t)(b * 2048 + s0 + ty + i) * 3072 + 2048 + h * 64 + d0 + tx];
    __syncthreads();
#pragma unroll
    for (int i = 0; i < 32; i += 8)
        vt[((size_t)bh * 64 + d0 + ty + i) * 2048 + s0 + tx] = tile[tx][ty + i];
}

// ---------------------------------------------------------------------------
__global__ void concat3_k(const float* a, const float* b, const float* c, float* out)
{
    int i = blockIdx.x * 256 + threadIdx.x;
    if (i < 3072) out[i] = (i < 1024) ? a[i] : (i < 2048 ? b[i - 1024] : c[i - 2048]);
}

// ---------------------------------------------------------------------------
// mask dtype detection: 0 = int32 0/1, 1 = packed bytes, 2 = f32 0/1
// ---------------------------------------------------------------------------
__global__ __launch_bounds__(1024) void detect_mask_k(
    const unsigned int* __restrict__ m, int* __restrict__ flag)
{
    __shared__ int f1, f2;
    if (threadIdx.x == 0) { f1 = 0; f2 = 0; }
    __syncthreads();
    int l1 = 0, l2 = 0;
    for (int i = threadIdx.x; i < 65536; i += 1024) {
        unsigned v = m[i];
        l1 |= (v > 1u);
        l2 |= (v != 0u && v != 0x3f800000u);
    }
    if (l1) atomicOr(&f1, 1);
    if (l2) atomicOr(&f2, 1);
    __syncthreads();
    if (threadIdx.x == 0) {
        int mode = 0;
        if (f1) mode = f2 ? 1 : 2;
        *flag = mode;
    }
}

// ---------------------------------------------------------------------------
// 256x256 8-phase GEMM (T1+T2+T3+T4+T5): C(M,N) = A(M,K) @ Bt(N,K)^T + bias
//   EPI 0: store bf16.  EPI 1: relu, store bf16.
// 512 threads = 8 waves (2M x 4N), BK=64, LDS 128 KiB double-buffered,
// st_16x32 swizzle, counted vmcnt(4) at phases 4/8 only, setprio around MFMA.
// Requires M%256==0, N%256==0, K%128==0.
// ---------------------------------------------------------------------------
template<int EPI>
__global__ __launch_bounds__(512) void gemm256_bt(
    const unsigned short* __restrict__ A, const unsigned short* __restrict__ Bt,
    const float* __restrict__ bias, void* __restrict__ Cout,
    int M, int N, int K)
{
    // [dbuf][A/B][256 rows][64 cols] bf16 = 128 KiB
    __shared__ __align__(16) unsigned short lds[2][2][256 * 64];
    const int t = threadIdx.x;
    const int lane = t & 63;
    const int wid = t >> 6;
    const int l16 = lane & 15, g = lane >> 4;
    const int wr = wid >> 2, wc = wid & 3;   // 2M x 4N wave grid

    // T1: bijective XCD swizzle on linear block id (m204 formula, NXCD=8)
    const int nbx = gridDim.x, nwg = nbx * gridDim.y;
    const int orig = blockIdx.y * nbx + blockIdx.x;
    const int qq = nwg >> 3, rr = nwg & 7;
    const int xcd = orig & 7, idx = orig >> 3;
    const int wg = (xcd < rr) ? (xcd * (qq + 1) + idx)
                              : (rr * (qq + 1) + (xcd - rr) * qq + idx);
    const int bm = (wg / nbx) * 256, bn = (wg % nbx) * 256;

    const int ntiles = K >> 6;
    auto kof = [&](int s) { return (s < ntiles ? s : ntiles - 1) << 6; };

    auto stage_half = [&](const unsigned short* __restrict__ P, int grow0, int k0,
                          int buf, int ab, int half) {
#pragma unroll
        for (int rnd = 0; rnd < 2; ++rnd) {
            const int off = rnd * 8192 + t * 16;        // byte offset in 16 KiB half
            const int sw  = SWZ(off);
            const int row = off >> 7;                   // 0..127
            const int col = (sw & 127) >> 1;            // bf16 col 0..63
            gload16(&P[(size_t)(grow0 + half * 128 + row) * K + k0 + col],
                    &lds[buf][ab][half * 8192 + (off >> 1)]);
        }
    };

    auto lda = [&](int buf, int m, int kc) -> short8 {
        const int byte = ((m * 32 + wr * 16 + l16) * 64 + kc * 32 + g * 8) * 2;
        return *(const short8*)((const char*)&lds[buf][0][0] + SWZ(byte));
    };
    auto ldb = [&](int buf, int n, int kc) -> short8 {
        const int byte = ((n * 64 + wc * 16 + l16) * 64 + kc * 32 + g * 8) * 2;
        return *(const short8*)((const char*)&lds[buf][1][0] + SWZ(byte));
    };

    f32x4 acc[8][4] = {};
    short8 af[4][2];

    stage_half(A,  bm, 0,  0, 0, 0);
    stage_half(A,  bm, 0,  0, 0, 1);
    stage_half(Bt, bn, 0,  0, 1, 0);
    stage_half(Bt, bn, 0,  0, 1, 1);
    stage_half(A,  bm, 64, 1, 0, 0);
    stage_half(Bt, bn, 64, 1, 1, 0);
    asm volatile("s_waitcnt vmcnt(4)" ::: "memory");   // tile0 resident
    __builtin_amdgcn_s_barrier();

#define PH(buf, mh, nh, doLoadA, STAGE_STMT, doVM)                                  \
  {                                                                                  \
    if (doLoadA) {                                                                   \
      _Pragma("unroll") for (int mm = 0; mm < 4; ++mm)                               \
      _Pragma("unroll") for (int kc = 0; kc < 2; ++kc)                               \
        af[mm][kc] = lda(buf, (mh) * 4 + mm, kc);                                    \
    }                                                                                \
    short8 bf[2][2];                                                                 \
    _Pragma("unroll") for (int nn = 0; nn < 2; ++nn)                                 \
    _Pragma("unroll") for (int kc = 0; kc < 2; ++kc)                                 \
      bf[nn][kc] = ldb(buf, (nh) * 2 + nn, kc);                                      \
    STAGE_STMT;                                                                      \
    __builtin_amdgcn_s_barrier();                                                    \
    __builtin_amdgcn_s_setprio(1);                                                   \
    _Pragma("unroll") for (int mm = 0; mm < 4; ++mm)                                 \
    _Pragma("unroll") for (int nn = 0; nn < 2; ++nn)                                 \
    _Pragma("unroll") for (int kc = 0; kc < 2; ++kc)                                 \
      acc[(mh) * 4 + mm][(nh) * 2 + nn] = __builtin_amdgcn_mfma_f32_16x16x32_bf16(   \
          af[mm][kc], bf[nn][kc], acc[(mh) * 4 + mm][(nh) * 2 + nn], 0, 0, 0);       \
    __builtin_amdgcn_s_setprio(0);                                                   \
    if (doVM) { asm volatile("s_waitcnt vmcnt(4)" ::: "memory"); }                   \
    __builtin_amdgcn_s_barrier();                                                    \
  }

    const int half_ntiles = ntiles >> 1;
    for (int i = 0; i < half_ntiles; ++i) {
        const int k1 = (2 * i + 1) << 6;
        const int k2 = kof(2 * i + 2);
        const int k3 = kof(2 * i + 3);
        PH(0, 0, 0, 1, (stage_half(A,  bm, k1, 1, 0, 1)), 0)
        PH(0, 0, 1, 0, (stage_half(Bt, bn, k1, 1, 1, 1)), 0)
        PH(0, 1, 0, 1, (stage_half(A,  bm, k2, 0, 0, 0)), 0)
        PH(0, 1, 1, 0, (stage_half(Bt, bn, k2, 0, 1, 0)), 1)
        PH(1, 0, 0, 1, (stage_half(A,  bm, k2, 0, 0, 1)), 0)
        PH(1, 0, 1, 0, (stage_half(Bt, bn, k2, 0, 1, 1)), 0)
        PH(1, 1, 0, 1, (stage_half(A,  bm, k3, 1, 0, 0)), 0)
        PH(1, 1, 1, 0, (stage_half(Bt, bn, k3, 1, 1, 0)), 1)
    }
#undef PH

#pragma unroll
    for (int m = 0; m < 8; ++m) {
        const int row0 = bm + m * 32 + wr * 16 + g * 4;
#pragma unroll
        for (int n = 0; n < 4; ++n) {
            const int col = bn + n * 64 + wc * 16 + l16;
            const float bb = bias[col];
#pragma unroll
            for (int r = 0; r < 4; ++r) {
                float v = acc[m][n][r] + bb;
                if (EPI == 1) v = fmaxf(v, 0.f);
                ((unsigned short*)Cout)[(size_t)(row0 + r) * N + col] = f2bf(v);
            }
        }
    }
}

// ---------------------------------------------------------------------------
// 128x128 GEMM (m97 structure): used for Wo and FF2 (EPI 2: +resid, f32 out)
// ---------------------------------------------------------------------------
template<int EPI>
__global__ __launch_bounds__(256) void gemm_bt(
    const unsigned short* __restrict__ A, const unsigned short* __restrict__ Bt,
    const float* __restrict__ bias, const float* __restrict__ resid,
    void* __restrict__ Cout, int M, int N, int K)
{
    __shared__ unsigned short As[128 * 64];
    __shared__ unsigned short Bs[128 * 64];
    const int t = threadIdx.x;
    const int lane = t & 63, wid = t >> 6;
    const int l16 = lane & 15, g = lane >> 4;
    const int wr = wid >> 1, wc = wid & 1;
    const int bm = blockIdx.y * 128, bn = blockIdx.x * 128;

    f32x4 acc[4][4] = {};

    for (int k0 = 0; k0 < K; k0 += 64) {
        __syncthreads();
#pragma unroll
        for (int i = 0; i < 4; ++i) {
            int linear = i * 2048 + t * 8;
            int row = linear >> 6, col = linear & 63;
            gload16(&A[(size_t)(bm + row) * K + k0 + col], &As[linear]);
        }
#pragma unroll
        for (int i = 0; i < 4; ++i) {
            int linear = i * 2048 + t * 8;
            int row = linear >> 6, col = linear & 63;
            gload16(&Bt[(size_t)(bn + row) * K + k0 + col], &Bs[linear]);
        }
        __syncthreads();
#pragma unroll
        for (int kc = 0; kc < 2; ++kc) {
            short8 a[4], b[4];
#pragma unroll
            for (int m = 0; m < 4; ++m)
                a[m] = *(const short8*)&As[(wr * 64 + m * 16 + l16) * 64 + kc * 32 + g * 8];
#pragma unroll
            for (int n = 0; n < 4; ++n)
                b[n] = *(const short8*)&Bs[(wc * 64 + n * 16 + l16) * 64 + kc * 32 + g * 8];
#pragma unroll
            for (int m = 0; m < 4; ++m)
#pragma unroll
                for (int n = 0; n < 4; ++n)
                    acc[m][n] = __builtin_amdgcn_mfma_f32_16x16x32_bf16(a[m], b[n], acc[m][n], 0, 0, 0);
        }
    }

#pragma unroll
    for (int m = 0; m < 4; ++m) {
        const int row0 = bm + wr * 64 + m * 16 + g * 4;
#pragma unroll
        for (int n = 0; n < 4; ++n) {
            const int col = bn + wc * 64 + n * 16 + l16;
            const float bb = bias[col];
#pragma unroll
            for (int r = 0; r < 4; ++r) {
                float v = acc[m][n][r] + bb;
                const size_t idx = (size_t)(row0 + r) * N + col;
                if (EPI == 2) {
                    ((float*)Cout)[idx] = v + resid[idx];
                } else {
                    if (EPI == 1) v = fmaxf(v, 0.f);
                    ((unsigned short*)Cout)[idx] = f2bf(v);
                }
            }
        }
    }
}

// ---------------------------------------------------------------------------
// Flash attention; mask ballot-packed inline; global V^T; barrier-free loop.
// grid: (S/64, B*H). block: 256 thr = 4 waves; wave w handles 16 q-rows.
// ---------------------------------------------------------------------------
__global__ __launch_bounds__(256) void attn_k(
    const unsigned short* __restrict__ qkv,
    const unsigned short* __restrict__ vt,
    const void* __restrict__ mask,
    const int* __restrict__ flag,
    unsigned short* __restrict__ ctx)
{
    __shared__ unsigned short Pl[4][16 * 72];
    const int t = threadIdx.x, lane = t & 63, w = t >> 6;
    const int l16 = lane & 15, g = lane >> 4;
    const int bh = blockIdx.y;
    const int b = bh >> 4, h = bh & 15;
    const int q0 = blockIdx.x * 64;
    const int mode = *flag;

    const size_t rowQ = (size_t)(b * 2048 + q0 + w * 16 + l16) * 3072 + h * 64;
    const short8 qf0 = *(const short8*)&qkv[rowQ + g * 8];
    const short8 qf1 = *(const short8*)&qkv[rowQ + 32 + g * 8];

    // mask rows for this wave's 16 q-rows (row r -> q = q0 + w*16 + r)
    const size_t mrow0 = ((size_t)bh * 2048 + q0 + w * 16) * 2048;
    const unsigned short* vbase = &vt[(size_t)bh * 64 * 2048];

    f32x4 acc[4] = {};
    float mrow[4], lrow[4];
#pragma unroll
    for (int j = 0; j < 4; ++j) { mrow[j] = -INFINITY; lrow[j] = 0.f; }

    for (int kt = 0; kt < 32; ++kt) {
        // ballot-pack 16 q-rows of mask: bit l of bl[r] = keep(q-row r, k=kt*64+l)
        unsigned long long bl[16];
        if (mode == 0) {
            const int* m = (const int*)mask;
#pragma unroll
            for (int r = 0; r < 16; ++r)
                bl[r] = __ballot(m[mrow0 + (size_t)r * 2048 + kt * 64 + lane] != 0);
        } else if (mode == 1) {
            const unsigned char* m = (const unsigned char*)mask;
#pragma unroll
            for (int r = 0; r < 16; ++r)
                bl[r] = __ballot(m[mrow0 + (size_t)r * 2048 + kt * 64 + lane] != 0);
        } else {
            const float* m = (const float*)mask;
#pragma unroll
            for (int r = 0; r < 16; ++r)
                bl[r] = __ballot(m[mrow0 + (size_t)r * 2048 + kt * 64 + lane] != 0.f);
        }
        // thread's j-th q-row is r = g*4 + j: select among the 16 uniform words
        unsigned long long mw[4];
#pragma unroll
        for (int j = 0; j < 4; ++j) {
            const unsigned long long v01 = (g & 1) ? bl[4 + j] : bl[j];
            const unsigned long long v23 = (g & 1) ? bl[12 + j] : bl[8 + j];
            mw[j] = (g & 2) ? v23 : v01;
        }

        // S = Q K^T
        f32x4 s[4] = {};
        __builtin_amdgcn_s_setprio(1);
#pragma unroll
        for (int n = 0; n < 4; ++n) {
            const size_t rowK = (size_t)(b * 2048 + kt * 64 + n * 16 + l16) * 3072 + 1024 + h * 64;
            const short8 kf0 = *(const short8*)&qkv[rowK + g * 8];
            const short8 kf1 = *(const short8*)&qkv[rowK + 32 + g * 8];
            s[n] = __builtin_amdgcn_mfma_f32_16x16x32_bf16(qf0, kf0, s[n], 0, 0, 0);
            s[n] = __builtin_amdgcn_mfma_f32_16x16x32_bf16(qf1, kf1, s[n], 0, 0, 0);
        }
        __builtin_amdgcn_s_setprio(0);

        // scale + mask: element (q = g*4+j, k-bit = n*16+l16)
#pragma unroll
        for (int n = 0; n < 4; ++n) {
            const int sh = n * 16 + l16;
#pragma unroll
            for (int j = 0; j < 4; ++j) {
                const bool keep = (mw[j] >> sh) & 1ull;
                s[n][j] = keep ? s[n][j] * 0.125f : -1e30f;
            }
        }

        // online softmax per q-row
#pragma unroll
        for (int j = 0; j < 4; ++j) {
            float mx = fmaxf(fmaxf(s[0][j], s[1][j]), fmaxf(s[2][j], s[3][j]));
#pragma unroll
            for (int d = 1; d < 16; d <<= 1) mx = fmaxf(mx, __shfl_xor(mx, d));
            const float mn = fmaxf(mrow[j], mx);
            float p0 = __expf(s[0][j] - mn), p1 = __expf(s[1][j] - mn);
            float p2 = __expf(s[2][j] - mn), p3 = __expf(s[3][j] - mn);
            s[0][j] = p0; s[1][j] = p1; s[2][j] = p2; s[3][j] = p3;
            float sm = p0 + p1 + p2 + p3;
#pragma unroll
            for (int d = 1; d < 16; d <<= 1) sm += __shfl_xor(sm, d);
            const float scale = __expf(mrow[j] - mn);
            lrow[j] = lrow[j] * scale + sm;
            mrow[j] = mn;
#pragma unroll
            for (int n = 0; n < 4; ++n) acc[n][j] *= scale;
        }

        // P (f32, C-layout) -> bf16 -> per-wave LDS [q][kk] (wave-local)
#pragma unroll
        for (int n = 0; n < 4; ++n)
#pragma unroll
            for (int j = 0; j < 4; ++j)
                Pl[w][(g * 4 + j) * 72 + n * 16 + l16] = f2bf(s[n][j]);

        // O += P V
        __builtin_amdgcn_s_setprio(1);
#pragma unroll
        for (int c = 0; c < 2; ++c) {
            const short8 pf = *(const short8*)&Pl[w][l16 * 72 + c * 32 + g * 8];
#pragma unroll
            for (int n = 0; n < 4; ++n) {
                const short8 vf = *(const short8*)&vbase[(size_t)(n * 16 + l16) * 2048 + kt * 64 + c * 32 + g * 8];
                acc[n] = __builtin_amdgcn_mfma_f32_16x16x32_bf16(pf, vf, acc[n], 0, 0, 0);
            }
        }
        __builtin_amdgcn_s_setprio(0);
    }

#pragma unroll
    for (int n = 0; n < 4; ++n)
#pragma unroll
        for (int j = 0; j < 4; ++j) {
            const int q = q0 + w * 16 + g * 4 + j;
            ctx[(size_t)(b * 2048 + q) * 1024 + h * 64 + n * 16 + l16] = f2bf(acc[n][j] / lrow[j]);
        }
}

// ---------------------------------------------------------------------------
// row LayerNorm over 1024. WB=1: also write bf16 copy.
// ---------------------------------------------------------------------------
template<int WB>
__global__ __launch_bounds__(256) void ln_k(
    const float* __restrict__ in, const float* __restrict__ gw, const float* __restrict__ bw,
    float* __restrict__ outF, unsigned short* __restrict__ outB)
{
    __shared__ float red[2][4];
    const int row = blockIdx.x, t = threadIdx.x;
    const f32x4 v = *(const f32x4*)&in[(size_t)row * 1024 + t * 4];
    float s = v[0] + v[1] + v[2] + v[3];
    float ss = v[0] * v[0] + v[1] * v[1] + v[2] * v[2] + v[3] * v[3];
#pragma unroll
    for (int d = 1; d < 64; d <<= 1) { s += __shfl_xor(s, d); ss += __shfl_xor(ss, d); }
    if ((t & 63) == 0) { red[0][t >> 6] = s; red[1][t >> 6] = ss; }
    __syncthreads();
    s = red[0][0] + red[0][1] + red[0][2] + red[0][3];
    ss = red[1][0] + red[1][1] + red[1][2] + red[1][3];
    const float mu = s * (1.f / 1024.f);
    const float var = ss * (1.f / 1024.f) - mu * mu;
    const float rs = rsqrtf(var + 1e-5f);
    f32x4 y;
#pragma unroll
    for (int e = 0; e < 4; ++e)
        y[e] = (v[e] - mu) * rs * gw[t * 4 + e] + bw[t * 4 + e];
    *(f32x4*)&outF[(size_t)row * 1024 + t * 4] = y;
    if (WB) {
        u16x4 o = { f2bf(y[0]), f2bf(y[1]), f2bf(y[2]), f2bf(y[3]) };
        *(u16x4*)&outB[(size_t)row * 1024 + t * 4] = o;
    }
}

// ---------------------------------------------------------------------------
extern "C" void kernel_launch(void* const* d_in, const int* in_sizes, int n_in,
                              void* d_out, int out_size, void* d_ws, size_t ws_size,
                              hipStream_t stream)
{
    (void)n_in; (void)out_size; (void)ws_size;
    const float* x   = (const float*)d_in[0];
    const void*  mask = d_in[1];
    const float* Wq  = (const float*)d_in[2];
    const float* bq  = (const float*)d_in[3];
    const float* Wk  = (const float*)d_in[4];
    const float* bk  = (const float*)d_in[5];
    const float* Wv  = (const float*)d_in[6];
    const float* bv  = (const float*)d_in[7];
    const float* Wo  = (const float*)d_in[8];
    const float* bo  = (const float*)d_in[9];
    const float* g1  = (const float*)d_in[10];
    const float* be1 = (const float*)d_in[11];
    const float* g2  = (const float*)d_in[12];
    const float* be2 = (const float*)d_in[13];
    const float* W1  = (const float*)d_in[14];
    const float* b1  = (const float*)d_in[15];
    const float* W2  = (const float*)d_in[16];
    const float* b2  = (const float*)d_in[17];

    const int M = 4096;   // B*S

    char* wsb = (char*)d_ws;
    size_t off = 0;
    auto alloc = [&](size_t bytes) -> char* {
        char* p = wsb + off;
        off += (bytes + 255) & ~(size_t)255;
        return p;
    };
    int*            flag   = (int*)           alloc(256);
    unsigned short* xb     = (unsigned short*)alloc((size_t)M * 1024 * 2);
    unsigned short* wqkvT  = (unsigned short*)alloc((size_t)3072 * 1024 * 2);
    unsigned short* woT    = (unsigned short*)alloc((size_t)1024 * 1024 * 2);
    unsigned short* w1T    = (unsigned short*)alloc((size_t)4096 * 1024 * 2);
    unsigned short* w2T    = (unsigned short*)alloc((size_t)1024 * 4096 * 2);
    float*          bqkv   = (float*)         alloc(3072 * 4);
    unsigned short* qkv    = (unsigned short*)alloc((size_t)M * 3072 * 2);
    unsigned short* vtb    = (unsigned short*)alloc((size_t)32 * 64 * 2048 * 2);
    unsigned short* ctxb   = (unsigned short*)alloc((size_t)M * 1024 * 2);
    float*          r1f    = (float*)         alloc((size_t)M * 1024 * 4);
    float*          x1f    = (float*)         alloc((size_t)M * 1024 * 4);
    unsigned short* x1b    = (unsigned short*)alloc((size_t)M * 1024 * 2);
    unsigned short* hb     = (unsigned short*)alloc((size_t)M * 4096 * 2);

    detect_mask_k<<<1, 1024, 0, stream>>>((const unsigned int*)mask, flag);
    f32_to_bf16_k<<<4096, 256, 0, stream>>>(x, xb, M * 1024 / 4);
    transpose_k<<<dim3(32, 32),  256, 0, stream>>>(Wq, wqkvT,                1024, 1024);
    transpose_k<<<dim3(32, 32),  256, 0, stream>>>(Wk, wqkvT + 1024 * 1024,  1024, 1024);
    transpose_k<<<dim3(32, 32),  256, 0, stream>>>(Wv, wqkvT + 2048 * 1024,  1024, 1024);
    transpose_k<<<dim3(32, 32),  256, 0, stream>>>(Wo, woT,                  1024, 1024);
    transpose_k<<<dim3(128, 32), 256, 0, stream>>>(W1, w1T, 1024, 4096);
    transpose_k<<<dim3(32, 128), 256, 0, stream>>>(W2, w2T, 4096, 1024);
    concat3_k<<<12, 256, 0, stream>>>(bq, bk, bv, bqkv);

    // QKV projection: 8-phase 256^2 (192 blocks)
    gemm256_bt<0><<<dim3(12, 16), 512, 0, stream>>>(xb, wqkvT, bqkv, qkv, M, 3072, 1024);
    // per-head V^T
    vtrans_k<<<dim3(64, 2, 32), 256, 0, stream>>>(qkv, vtb);
    // attention (mask ballot-packed inline) -> ctx bf16
    attn_k<<<dim3(32, 32), 256, 0, stream>>>(qkv, vtb, mask, flag, ctxb);
    // attn_out + residual: r1 = ctx@Wo + bo + x  (f32)
    gemm_bt<2><<<dim3(8, 32), 256, 0, stream>>>(ctxb, woT, bo, x, r1f, M, 1024, 1024);
    // LN1 -> x1 (f32 + bf16)
    ln_k<1><<<4096, 256, 0, stream>>>(r1f, g1, be1, x1f, x1b);
    // FF1: relu(x1@W1 + b1) -> hb bf16 : 8-phase 256^2 (256 blocks)
    gemm256_bt<1><<<dim3(16, 16), 512, 0, stream>>>(x1b, w1T, b1, hb, M, 4096, 1024);
    // FF2 + residual: r1 = hb@W2 + b2 + x1  (f32)
    gemm_bt<2><<<dim3(8, 32), 256, 0, stream>>>(hb, w2T, b2, x1f, r1f, M, 1024, 4096);
    // LN2 -> out
    ln_k<0><<<4096, 256, 0, stream>>>(r1f, g2, be2, (float*)d_out, nullptr);
}

// Round 6
// 1286.028 us; speedup vs baseline: 1.2469x; 1.2469x over previous
//
#include <hip/hip_runtime.h>
#include <stdint.h>

// ---------------------------------------------------------------------------
// HiSA transformer block on MI355X (gfx950), bf16-MFMA implementation.
// B=2, S=2048, D=1024, H=16, dk=64, F=4096.
// R5 (resubmit; prior attempt hit GPU-acquisition timeout):
//     packed-mask pre-pass restored (R4's inline ballot serialized);
//     attention softmax rebuilt WITHOUT online max -> zero cross-lane ops
//     in the kt loop (exp direct, masked->0, epilogue-only denom reduce).
// ---------------------------------------------------------------------------

typedef __attribute__((ext_vector_type(8))) short short8;     // 8 bf16 (4 VGPRs)
typedef __attribute__((ext_vector_type(4))) float f32x4;      // MFMA C/D frag
typedef __attribute__((ext_vector_type(4))) unsigned short u16x4;

__device__ __forceinline__ unsigned short f2bf(float f) {
    union { float f; unsigned u; } v; v.f = f;
    unsigned r = v.u + 0x7fffu + ((v.u >> 16) & 1u);   // round-to-nearest-even
    return (unsigned short)(r >> 16);
}

// async global->LDS, 16B per lane. LDS dest must be wave-uniform base + lane*16.
__device__ __forceinline__ void gload16(const void* gsrc, void* ldst) {
    __builtin_amdgcn_global_load_lds(
        (const __attribute__((address_space(1))) void*)gsrc,
        (__attribute__((address_space(3))) void*)ldst,
        16, 0, 0);
}

// st_16x32 XOR swizzle: toggle byte-bit5 with byte-bit9 (within 1KB subtile)
__device__ __forceinline__ int SWZ(int b) { return b ^ (((b >> 9) & 1) << 5); }

// ---------------------------------------------------------------------------
// f32 -> bf16 elementwise convert (vectorized)
// ---------------------------------------------------------------------------
__global__ __launch_bounds__(256) void f32_to_bf16_k(
    const float* __restrict__ in, unsigned short* __restrict__ out, int n4)
{
    int i = blockIdx.x * 256 + threadIdx.x;
    if (i < n4) {
        f32x4 v = *(const f32x4*)&in[(size_t)i * 4];
        u16x4 o = { f2bf(v[0]), f2bf(v[1]), f2bf(v[2]), f2bf(v[3]) };
        *(u16x4*)&out[(size_t)i * 4] = o;
    }
}

// ---------------------------------------------------------------------------
// W (K x N, f32) -> Wt (N x K, bf16) tiled transpose
// ---------------------------------------------------------------------------
__global__ __launch_bounds__(256) void transpose_k(
    const float* __restrict__ W, unsigned short* __restrict__ Wt, int K, int N)
{
    __shared__ float tile[32][33];
    const int n0 = blockIdx.x * 32, k0 = blockIdx.y * 32;
    const int tx = threadIdx.x & 31, ty = threadIdx.x >> 5;  // ty in [0,8)
#pragma unroll
    for (int i = 0; i < 32; i += 8)
        tile[ty + i][tx] = W[(size_t)(k0 + ty + i) * N + n0 + tx];
    __syncthreads();
#pragma unroll
    for (int i = 0; i < 32; i += 8)
        Wt[(size_t)(n0 + ty + i) * K + k0 + tx] = f2bf(tile[tx][ty + i]);
}

// ---------------------------------------------------------------------------
// per-head V^T: vt[(bh*64 + d)*2048 + s] = V[b, s, h, d]
// ---------------------------------------------------------------------------
__global__ __launch_bounds__(256) void vtrans_k(
    const unsigned short* __restrict__ qkv, unsigned short* __restrict__ vt)
{
    __shared__ unsigned short tile[32][34];
    const int s0 = blockIdx.x * 32;
    const int d0 = blockIdx.y * 32;
    const int bh = blockIdx.z, b = bh >> 4, h = bh & 15;
    const int tx = threadIdx.x & 31, ty = threadIdx.x >> 5;
#pragma unroll
    for (int i = 0; i < 32; i += 8)
        tile[ty + i][tx] = qkv[(size_t)(b * 2048 + s0 + ty + i) * 3072 + 2048 + h * 64 + d0 + tx];
    __syncthreads();
#pragma unroll
    for (int i = 0; i < 32; i += 8)
        vt[((size_t)bh * 64 + d0 + ty + i) * 2048 + s0 + tx] = tile[tx][ty + i];
}

// ---------------------------------------------------------------------------
__global__ void concat3_k(const float* a, const float* b, const float* c, float* out)
{
    int i = blockIdx.x * 256 + threadIdx.x;
    if (i < 3072) out[i] = (i < 1024) ? a[i] : (i < 2048 ? b[i - 1024] : c[i - 2048]);
}

// ---------------------------------------------------------------------------
// mask dtype detection: 0 = int32 0/1, 1 = packed bytes, 2 = f32 0/1
// ---------------------------------------------------------------------------
__global__ __launch_bounds__(1024) void detect_mask_k(
    const unsigned int* __restrict__ m, int* __restrict__ flag)
{
    __shared__ int f1, f2;
    if (threadIdx.x == 0) { f1 = 0; f2 = 0; }
    __syncthreads();
    int l1 = 0, l2 = 0;
    for (int i = threadIdx.x; i < 65536; i += 1024) {
        unsigned v = m[i];
        l1 |= (v > 1u);
        l2 |= (v != 0u && v != 0x3f800000u);
    }
    if (l1) atomicOr(&f1, 1);
    if (l2) atomicOr(&f2, 1);
    __syncthreads();
    if (threadIdx.x == 0) {
        int mode = 0;
        if (f1) mode = f2 ? 1 : 2;
        *flag = mode;
    }
}

// ---------------------------------------------------------------------------
// bit-pack mask: packed[i>>6] bit (i&63) = keep(element i)
// ---------------------------------------------------------------------------
__global__ __launch_bounds__(256) void pack_mask_k(
    const void* __restrict__ mask, const int* __restrict__ flag,
    unsigned long long* __restrict__ packed, long long nelem)
{
    const int mode = *flag;
    const long long stride = (long long)gridDim.x * 256;
    long long i = (long long)blockIdx.x * 256 + threadIdx.x;
    if (mode == 0) {
        const int* m = (const int*)mask;
        for (; i < nelem; i += stride) {
            unsigned long long bl = __ballot(m[i] != 0);
            if ((threadIdx.x & 63) == 0) packed[i >> 6] = bl;
        }
    } else if (mode == 1) {
        const unsigned char* m = (const unsigned char*)mask;
        for (; i < nelem; i += stride) {
            unsigned long long bl = __ballot(m[i] != 0);
            if ((threadIdx.x & 63) == 0) packed[i >> 6] = bl;
        }
    } else {
        const float* m = (const float*)mask;
        for (; i < nelem; i += stride) {
            unsigned long long bl = __ballot(m[i] != 0.f);
            if ((threadIdx.x & 63) == 0) packed[i >> 6] = bl;
        }
    }
}

// ---------------------------------------------------------------------------
// 256x256 8-phase GEMM (T1+T2+T3+T4+T5): C(M,N) = A(M,K) @ Bt(N,K)^T + bias
// ---------------------------------------------------------------------------
template<int EPI>
__global__ __launch_bounds__(512) void gemm256_bt(
    const unsigned short* __restrict__ A, const unsigned short* __restrict__ Bt,
    const float* __restrict__ bias, void* __restrict__ Cout,
    int M, int N, int K)
{
    __shared__ __align__(16) unsigned short lds[2][2][256 * 64];
    const int t = threadIdx.x;
    const int lane = t & 63;
    const int wid = t >> 6;
    const int l16 = lane & 15, g = lane >> 4;
    const int wr = wid >> 2, wc = wid & 3;   // 2M x 4N wave grid

    const int nbx = gridDim.x, nwg = nbx * gridDim.y;
    const int orig = blockIdx.y * nbx + blockIdx.x;
    const int qq = nwg >> 3, rr = nwg & 7;
    const int xcd = orig & 7, idx = orig >> 3;
    const int wg = (xcd < rr) ? (xcd * (qq + 1) + idx)
                              : (rr * (qq + 1) + (xcd - rr) * qq + idx);
    const int bm = (wg / nbx) * 256, bn = (wg % nbx) * 256;

    const int ntiles = K >> 6;
    auto kof = [&](int s) { return (s < ntiles ? s : ntiles - 1) << 6; };

    auto stage_half = [&](const unsigned short* __restrict__ P, int grow0, int k0,
                          int buf, int ab, int half) {
#pragma unroll
        for (int rnd = 0; rnd < 2; ++rnd) {
            const int off = rnd * 8192 + t * 16;
            const int sw  = SWZ(off);
            const int row = off >> 7;
            const int col = (sw & 127) >> 1;
            gload16(&P[(size_t)(grow0 + half * 128 + row) * K + k0 + col],
                    &lds[buf][ab][half * 8192 + (off >> 1)]);
        }
    };

    auto lda = [&](int buf, int m, int kc) -> short8 {
        const int byte = ((m * 32 + wr * 16 + l16) * 64 + kc * 32 + g * 8) * 2;
        return *(const short8*)((const char*)&lds[buf][0][0] + SWZ(byte));
    };
    auto ldb = [&](int buf, int n, int kc) -> short8 {
        const int byte = ((n * 64 + wc * 16 + l16) * 64 + kc * 32 + g * 8) * 2;
        return *(const short8*)((const char*)&lds[buf][1][0] + SWZ(byte));
    };

    f32x4 acc[8][4] = {};
    short8 af[4][2];

    stage_half(A,  bm, 0,  0, 0, 0);
    stage_half(A,  bm, 0,  0, 0, 1);
    stage_half(Bt, bn, 0,  0, 1, 0);
    stage_half(Bt, bn, 0,  0, 1, 1);
    stage_half(A,  bm, 64, 1, 0, 0);
    stage_half(Bt, bn, 64, 1, 1, 0);
    asm volatile("s_waitcnt vmcnt(4)" ::: "memory");
    __builtin_amdgcn_s_barrier();

#define PH(buf, mh, nh, doLoadA, STAGE_STMT, doVM)                                  \
  {                                                                                  \
    if (doLoadA) {                                                                   \
      _Pragma("unroll") for (int mm = 0; mm < 4; ++mm)                               \
      _Pragma("unroll") for (int kc = 0; kc < 2; ++kc)                               \
        af[mm][kc] = lda(buf, (mh) * 4 + mm, kc);                                    \
    }                                                                                \
    short8 bf[2][2];                                                                 \
    _Pragma("unroll") for (int nn = 0; nn < 2; ++nn)                                 \
    _Pragma("unroll") for (int kc = 0; kc < 2; ++kc)                                 \
      bf[nn][kc] = ldb(buf, (nh) * 2 + nn, kc);                                      \
    STAGE_STMT;                                                                      \
    __builtin_amdgcn_s_barrier();                                                    \
    __builtin_amdgcn_s_setprio(1);                                                   \
    _Pragma("unroll") for (int mm = 0; mm < 4; ++mm)                                 \
    _Pragma("unroll") for (int nn = 0; nn < 2; ++nn)                                 \
    _Pragma("unroll") for (int kc = 0; kc < 2; ++kc)                                 \
      acc[(mh) * 4 + mm][(nh) * 2 + nn] = __builtin_amdgcn_mfma_f32_16x16x32_bf16(   \
          af[mm][kc], bf[nn][kc], acc[(mh) * 4 + mm][(nh) * 2 + nn], 0, 0, 0);       \
    __builtin_amdgcn_s_setprio(0);                                                   \
    if (doVM) { asm volatile("s_waitcnt vmcnt(4)" ::: "memory"); }                   \
    __builtin_amdgcn_s_barrier();                                                    \
  }

    const int half_ntiles = ntiles >> 1;
    for (int i = 0; i < half_ntiles; ++i) {
        const int k1 = (2 * i + 1) << 6;
        const int k2 = kof(2 * i + 2);
        const int k3 = kof(2 * i + 3);
        PH(0, 0, 0, 1, (stage_half(A,  bm, k1, 1, 0, 1)), 0)
        PH(0, 0, 1, 0, (stage_half(Bt, bn, k1, 1, 1, 1)), 0)
        PH(0, 1, 0, 1, (stage_half(A,  bm, k2, 0, 0, 0)), 0)
        PH(0, 1, 1, 0, (stage_half(Bt, bn, k2, 0, 1, 0)), 1)
        PH(1, 0, 0, 1, (stage_half(A,  bm, k2, 0, 0, 1)), 0)
        PH(1, 0, 1, 0, (stage_half(Bt, bn, k2, 0, 1, 1)), 0)
        PH(1, 1, 0, 1, (stage_half(A,  bm, k3, 1, 0, 0)), 0)
        PH(1, 1, 1, 0, (stage_half(Bt, bn, k3, 1, 1, 0)), 1)
    }
#undef PH

#pragma unroll
    for (int m = 0; m < 8; ++m) {
        const int row0 = bm + m * 32 + wr * 16 + g * 4;
#pragma unroll
        for (int n = 0; n < 4; ++n) {
            const int col = bn + n * 64 + wc * 16 + l16;
            const float bb = bias[col];
#pragma unroll
            for (int r = 0; r < 4; ++r) {
                float v = acc[m][n][r] + bb;
                if (EPI == 1) v = fmaxf(v, 0.f);
                ((unsigned short*)Cout)[(size_t)(row0 + r) * N + col] = f2bf(v);
            }
        }
    }
}

// ---------------------------------------------------------------------------
// 128x128 GEMM (m97 structure): used for Wo and FF2 (EPI 2: +resid, f32 out)
// ---------------------------------------------------------------------------
template<int EPI>
__global__ __launch_bounds__(256) void gemm_bt(
    const unsigned short* __restrict__ A, const unsigned short* __restrict__ Bt,
    const float* __restrict__ bias, const float* __restrict__ resid,
    void* __restrict__ Cout, int M, int N, int K)
{
    __shared__ unsigned short As[128 * 64];
    __shared__ unsigned short Bs[128 * 64];
    const int t = threadIdx.x;
    const int lane = t & 63, wid = t >> 6;
    const int l16 = lane & 15, g = lane >> 4;
    const int wr = wid >> 1, wc = wid & 1;
    const int bm = blockIdx.y * 128, bn = blockIdx.x * 128;

    f32x4 acc[4][4] = {};

    for (int k0 = 0; k0 < K; k0 += 64) {
        __syncthreads();
#pragma unroll
        for (int i = 0; i < 4; ++i) {
            int linear = i * 2048 + t * 8;
            int row = linear >> 6, col = linear & 63;
            gload16(&A[(size_t)(bm + row) * K + k0 + col], &As[linear]);
        }
#pragma unroll
        for (int i = 0; i < 4; ++i) {
            int linear = i * 2048 + t * 8;
            int row = linear >> 6, col = linear & 63;
            gload16(&Bt[(size_t)(bn + row) * K + k0 + col], &Bs[linear]);
        }
        __syncthreads();
#pragma unroll
        for (int kc = 0; kc < 2; ++kc) {
            short8 a[4], b[4];
#pragma unroll
            for (int m = 0; m < 4; ++m)
                a[m] = *(const short8*)&As[(wr * 64 + m * 16 + l16) * 64 + kc * 32 + g * 8];
#pragma unroll
            for (int n = 0; n < 4; ++n)
                b[n] = *(const short8*)&Bs[(wc * 64 + n * 16 + l16) * 64 + kc * 32 + g * 8];
#pragma unroll
            for (int m = 0; m < 4; ++m)
#pragma unroll
                for (int n = 0; n < 4; ++n)
                    acc[m][n] = __builtin_amdgcn_mfma_f32_16x16x32_bf16(a[m], b[n], acc[m][n], 0, 0, 0);
        }
    }

#pragma unroll
    for (int m = 0; m < 4; ++m) {
        const int row0 = bm + wr * 64 + m * 16 + g * 4;
#pragma unroll
        for (int n = 0; n < 4; ++n) {
            const int col = bn + wc * 64 + n * 16 + l16;
            const float bb = bias[col];
#pragma unroll
            for (int r = 0; r < 4; ++r) {
                float v = acc[m][n][r] + bb;
                const size_t idx = (size_t)(row0 + r) * N + col;
                if (EPI == 2) {
                    ((float*)Cout)[idx] = v + resid[idx];
                } else {
                    if (EPI == 1) v = fmaxf(v, 0.f);
                    ((unsigned short*)Cout)[idx] = f2bf(v);
                }
            }
        }
    }
}

// ---------------------------------------------------------------------------
// Flash attention, packed mask, global V^T, NO online max:
//   P = keep ? exp(S/8) : 0 ;  denom accumulated in-thread (partial over
//   k = l16 mod 16), reduced across 16 lanes ONCE in the epilogue.
// Zero cross-lane ops and zero barriers in the kt loop.
// grid: (S/64, B*H). block: 256 thr = 4 waves; wave w handles 16 q-rows.
// ---------------------------------------------------------------------------
__global__ __launch_bounds__(256) void attn_k(
    const unsigned short* __restrict__ qkv,
    const unsigned short* __restrict__ vt,
    const unsigned long long* __restrict__ pmask,
    unsigned short* __restrict__ ctx)
{
    __shared__ unsigned short Pl[4][16 * 72];
    const int t = threadIdx.x, lane = t & 63, w = t >> 6;
    const int l16 = lane & 15, g = lane >> 4;
    const int bh = blockIdx.y;
    const int b = bh >> 4, h = bh & 15;
    const int q0 = blockIdx.x * 64;

    const size_t rowQ = (size_t)(b * 2048 + q0 + w * 16 + l16) * 3072 + h * 64;
    const short8 qf0 = *(const short8*)&qkv[rowQ + g * 8];
    const short8 qf1 = *(const short8*)&qkv[rowQ + 32 + g * 8];

    const unsigned long long* mbase =
        pmask + ((size_t)bh * 2048 + q0 + w * 16 + g * 4) * 32;
    const unsigned short* vbase = &vt[(size_t)bh * 64 * 2048];

    f32x4 acc[4] = {};
    float lrow[4] = { 0.f, 0.f, 0.f, 0.f };

    for (int kt = 0; kt < 32; ++kt) {
        unsigned long long mw[4];
#pragma unroll
        for (int j = 0; j < 4; ++j) mw[j] = mbase[j * 32 + kt];

        // S = Q K^T
        f32x4 s[4] = {};
        __builtin_amdgcn_s_setprio(1);
#pragma unroll
        for (int n = 0; n < 4; ++n) {
            const size_t rowK = (size_t)(b * 2048 + kt * 64 + n * 16 + l16) * 3072 + 1024 + h * 64;
            const short8 kf0 = *(const short8*)&qkv[rowK + g * 8];
            const short8 kf1 = *(const short8*)&qkv[rowK + 32 + g * 8];
            s[n] = __builtin_amdgcn_mfma_f32_16x16x32_bf16(qf0, kf0, s[n], 0, 0, 0);
            s[n] = __builtin_amdgcn_mfma_f32_16x16x32_bf16(qf1, kf1, s[n], 0, 0, 0);
        }
        __builtin_amdgcn_s_setprio(0);

        // P = keep ? exp(S/8) : 0 ; in-thread partial denominator
#pragma unroll
        for (int n = 0; n < 4; ++n) {
            const int sh = n * 16 + l16;
#pragma unroll
            for (int j = 0; j < 4; ++j) {
                const bool keep = (mw[j] >> sh) & 1ull;
                const float p = keep ? __expf(s[n][j] * 0.125f) : 0.f;
                s[n][j] = p;
                lrow[j] += p;
            }
        }

        // P -> bf16 -> per-wave LDS [q][kk] (wave-local, no barrier)
#pragma unroll
        for (int n = 0; n < 4; ++n)
#pragma unroll
            for (int j = 0; j < 4; ++j)
                Pl[w][(g * 4 + j) * 72 + n * 16 + l16] = f2bf(s[n][j]);

        // O += P V
        __builtin_amdgcn_s_setprio(1);
#pragma unroll
        for (int c = 0; c < 2; ++c) {
            const short8 pf = *(const short8*)&Pl[w][l16 * 72 + c * 32 + g * 8];
#pragma unroll
            for (int n = 0; n < 4; ++n) {
                const short8 vf = *(const short8*)&vbase[(size_t)(n * 16 + l16) * 2048 + kt * 64 + c * 32 + g * 8];
                acc[n] = __builtin_amdgcn_mfma_f32_16x16x32_bf16(pf, vf, acc[n], 0, 0, 0);
            }
        }
        __builtin_amdgcn_s_setprio(0);
    }

    // epilogue: complete the denominator across the 16-lane group (once)
#pragma unroll
    for (int j = 0; j < 4; ++j) {
#pragma unroll
        for (int d = 1; d < 16; d <<= 1) lrow[j] += __shfl_xor(lrow[j], d);
        lrow[j] = 1.f / fmaxf(lrow[j], 1e-30f);
    }

#pragma unroll
    for (int n = 0; n < 4; ++n)
#pragma unroll
        for (int j = 0; j < 4; ++j) {
            const int q = q0 + w * 16 + g * 4 + j;
            ctx[(size_t)(b * 2048 + q) * 1024 + h * 64 + n * 16 + l16] = f2bf(acc[n][j] * lrow[j]);
        }
}

// ---------------------------------------------------------------------------
// row LayerNorm over 1024. WB=1: also write bf16 copy.
// ---------------------------------------------------------------------------
template<int WB>
__global__ __launch_bounds__(256) void ln_k(
    const float* __restrict__ in, const float* __restrict__ gw, const float* __restrict__ bw,
    float* __restrict__ outF, unsigned short* __restrict__ outB)
{
    __shared__ float red[2][4];
    const int row = blockIdx.x, t = threadIdx.x;
    const f32x4 v = *(const f32x4*)&in[(size_t)row * 1024 + t * 4];
    float s = v[0] + v[1] + v[2] + v[3];
    float ss = v[0] * v[0] + v[1] * v[1] + v[2] * v[2] + v[3] * v[3];
#pragma unroll
    for (int d = 1; d < 64; d <<= 1) { s += __shfl_xor(s, d); ss += __shfl_xor(ss, d); }
    if ((t & 63) == 0) { red[0][t >> 6] = s; red[1][t >> 6] = ss; }
    __syncthreads();
    s = red[0][0] + red[0][1] + red[0][2] + red[0][3];
    ss = red[1][0] + red[1][1] + red[1][2] + red[1][3];
    const float mu = s * (1.f / 1024.f);
    const float var = ss * (1.f / 1024.f) - mu * mu;
    const float rs = rsqrtf(var + 1e-5f);
    f32x4 y;
#pragma unroll
    for (int e = 0; e < 4; ++e)
        y[e] = (v[e] - mu) * rs * gw[t * 4 + e] + bw[t * 4 + e];
    *(f32x4*)&outF[(size_t)row * 1024 + t * 4] = y;
    if (WB) {
        u16x4 o = { f2bf(y[0]), f2bf(y[1]), f2bf(y[2]), f2bf(y[3]) };
        *(u16x4*)&outB[(size_t)row * 1024 + t * 4] = o;
    }
}

// ---------------------------------------------------------------------------
extern "C" void kernel_launch(void* const* d_in, const int* in_sizes, int n_in,
                              void* d_out, int out_size, void* d_ws, size_t ws_size,
                              hipStream_t stream)
{
    (void)n_in; (void)out_size; (void)ws_size;
    const float* x   = (const float*)d_in[0];
    const void*  mask = d_in[1];
    const float* Wq  = (const float*)d_in[2];
    const float* bq  = (const float*)d_in[3];
    const float* Wk  = (const float*)d_in[4];
    const float* bk  = (const float*)d_in[5];
    const float* Wv  = (const float*)d_in[6];
    const float* bv  = (const float*)d_in[7];
    const float* Wo  = (const float*)d_in[8];
    const float* bo  = (const float*)d_in[9];
    const float* g1  = (const float*)d_in[10];
    const float* be1 = (const float*)d_in[11];
    const float* g2  = (const float*)d_in[12];
    const float* be2 = (const float*)d_in[13];
    const float* W1  = (const float*)d_in[14];
    const float* b1  = (const float*)d_in[15];
    const float* W2  = (const float*)d_in[16];
    const float* b2  = (const float*)d_in[17];

    const int M = 4096;   // B*S
    const long long maskN = in_sizes[1];

    char* wsb = (char*)d_ws;
    size_t off = 0;
    auto alloc = [&](size_t bytes) -> char* {
        char* p = wsb + off;
        off += (bytes + 255) & ~(size_t)255;
        return p;
    };
    int*            flag   = (int*)           alloc(256);
    unsigned long long* pm = (unsigned long long*)alloc((size_t)(maskN / 64) * 8);
    unsigned short* xb     = (unsigned short*)alloc((size_t)M * 1024 * 2);
    unsigned short* wqkvT  = (unsigned short*)alloc((size_t)3072 * 1024 * 2);
    unsigned short* woT    = (unsigned short*)alloc((size_t)1024 * 1024 * 2);
    unsigned short* w1T    = (unsigned short*)alloc((size_t)4096 * 1024 * 2);
    unsigned short* w2T    = (unsigned short*)alloc((size_t)1024 * 4096 * 2);
    float*          bqkv   = (float*)         alloc(3072 * 4);
    unsigned short* qkv    = (unsigned short*)alloc((size_t)M * 3072 * 2);
    unsigned short* vtb    = (unsigned short*)alloc((size_t)32 * 64 * 2048 * 2);
    unsigned short* ctxb   = (unsigned short*)alloc((size_t)M * 1024 * 2);
    float*          r1f    = (float*)         alloc((size_t)M * 1024 * 4);
    float*          x1f    = (float*)         alloc((size_t)M * 1024 * 4);
    unsigned short* x1b    = (unsigned short*)alloc((size_t)M * 1024 * 2);
    unsigned short* hb     = (unsigned short*)alloc((size_t)M * 4096 * 2);

    detect_mask_k<<<1, 1024, 0, stream>>>((const unsigned int*)mask, flag);
    pack_mask_k<<<2048, 256, 0, stream>>>(mask, flag, pm, maskN);
    f32_to_bf16_k<<<4096, 256, 0, stream>>>(x, xb, M * 1024 / 4);
    transpose_k<<<dim3(32, 32),  256, 0, stream>>>(Wq, wqkvT,                1024, 1024);
    transpose_k<<<dim3(32, 32),  256, 0, stream>>>(Wk, wqkvT + 1024 * 1024,  1024, 1024);
    transpose_k<<<dim3(32, 32),  256, 0, stream>>>(Wv, wqkvT + 2048 * 1024,  1024, 1024);
    transpose_k<<<dim3(32, 32),  256, 0, stream>>>(Wo, woT,                  1024, 1024);
    transpose_k<<<dim3(128, 32), 256, 0, stream>>>(W1, w1T, 1024, 4096);
    transpose_k<<<dim3(32, 128), 256, 0, stream>>>(W2, w2T, 4096, 1024);
    concat3_k<<<12, 256, 0, stream>>>(bq, bk, bv, bqkv);

    // QKV projection: 8-phase 256^2 (192 blocks)
    gemm256_bt<0><<<dim3(12, 16), 512, 0, stream>>>(xb, wqkvT, bqkv, qkv, M, 3072, 1024);
    // per-head V^T
    vtrans_k<<<dim3(64, 2, 32), 256, 0, stream>>>(qkv, vtb);
    // attention -> ctx bf16
    attn_k<<<dim3(32, 32), 256, 0, stream>>>(qkv, vtb, pm, ctxb);
    // attn_out + residual: r1 = ctx@Wo + bo + x  (f32)
    gemm_bt<2><<<dim3(8, 32), 256, 0, stream>>>(ctxb, woT, bo, x, r1f, M, 1024, 1024);
    // LN1 -> x1 (f32 + bf16)
    ln_k<1><<<4096, 256, 0, stream>>>(r1f, g1, be1, x1f, x1b);
    // FF1: relu(x1@W1 + b1) -> hb bf16 : 8-phase 256^2 (256 blocks)
    gemm256_bt<1><<<dim3(16, 16), 512, 0, stream>>>(x1b, w1T, b1, hb, M, 4096, 1024);
    // FF2 + residual: r1 = hb@W2 + b2 + x1  (f32)
    gemm_bt<2><<<dim3(8, 32), 256, 0, stream>>>(hb, w2T, b2, x1f, r1f, M, 1024, 4096);
    // LN2 -> out
    ln_k<0><<<4096, 256, 0, stream>>>(r1f, g2, be2, (float*)d_out, nullptr);
}

// Round 8
// 1109.697 us; speedup vs baseline: 1.4450x; 1.1589x over previous
//
#include <hip/hip_runtime.h>
#include <stdint.h>

// ---------------------------------------------------------------------------
// HiSA transformer block on MI355X (gfx950), bf16-MFMA implementation.
// B=2, S=2048, D=1024, H=16, dk=64, F=4096.
// R7 (resubmit; prior attempt hit GPU-acquisition timeout):
//     attention restructured to 8-wave / 128-q-row blocks with LDS-staged,
//     XOR-swizzled, double-buffered K/V tiles (T3 2-phase, counted vmcnt(2));
//     no-max softmax retained.
// ---------------------------------------------------------------------------

typedef __attribute__((ext_vector_type(8))) short short8;     // 8 bf16 (4 VGPRs)
typedef __attribute__((ext_vector_type(4))) float f32x4;      // MFMA C/D frag
typedef __attribute__((ext_vector_type(4))) unsigned short u16x4;

__device__ __forceinline__ unsigned short f2bf(float f) {
    union { float f; unsigned u; } v; v.f = f;
    unsigned r = v.u + 0x7fffu + ((v.u >> 16) & 1u);   // round-to-nearest-even
    return (unsigned short)(r >> 16);
}

// async global->LDS, 16B per lane. LDS dest must be wave-uniform base + lane*16.
__device__ __forceinline__ void gload16(const void* gsrc, void* ldst) {
    __builtin_amdgcn_global_load_lds(
        (const __attribute__((address_space(1))) void*)gsrc,
        (__attribute__((address_space(3))) void*)ldst,
        16, 0, 0);
}

// st_16x32 XOR swizzle for gemm256 (byte-bit5 ^ byte-bit9)
__device__ __forceinline__ int SWZ(int b) { return b ^ (((b >> 9) & 1) << 5); }

// ---------------------------------------------------------------------------
// f32 -> bf16 elementwise convert (vectorized)
// ---------------------------------------------------------------------------
__global__ __launch_bounds__(256) void f32_to_bf16_k(
    const float* __restrict__ in, unsigned short* __restrict__ out, int n4)
{
    int i = blockIdx.x * 256 + threadIdx.x;
    if (i < n4) {
        f32x4 v = *(const f32x4*)&in[(size_t)i * 4];
        u16x4 o = { f2bf(v[0]), f2bf(v[1]), f2bf(v[2]), f2bf(v[3]) };
        *(u16x4*)&out[(size_t)i * 4] = o;
    }
}

// ---------------------------------------------------------------------------
// W (K x N, f32) -> Wt (N x K, bf16) tiled transpose
// ---------------------------------------------------------------------------
__global__ __launch_bounds__(256) void transpose_k(
    const float* __restrict__ W, unsigned short* __restrict__ Wt, int K, int N)
{
    __shared__ float tile[32][33];
    const int n0 = blockIdx.x * 32, k0 = blockIdx.y * 32;
    const int tx = threadIdx.x & 31, ty = threadIdx.x >> 5;  // ty in [0,8)
#pragma unroll
    for (int i = 0; i < 32; i += 8)
        tile[ty + i][tx] = W[(size_t)(k0 + ty + i) * N + n0 + tx];
    __syncthreads();
#pragma unroll
    for (int i = 0; i < 32; i += 8)
        Wt[(size_t)(n0 + ty + i) * K + k0 + tx] = f2bf(tile[tx][ty + i]);
}

// ---------------------------------------------------------------------------
// per-head V^T: vt[(bh*64 + d)*2048 + s] = V[b, s, h, d]
// ---------------------------------------------------------------------------
__global__ __launch_bounds__(256) void vtrans_k(
    const unsigned short* __restrict__ qkv, unsigned short* __restrict__ vt)
{
    __shared__ unsigned short tile[32][34];
    const int s0 = blockIdx.x * 32;
    const int d0 = blockIdx.y * 32;
    const int bh = blockIdx.z, b = bh >> 4, h = bh & 15;
    const int tx = threadIdx.x & 31, ty = threadIdx.x >> 5;
#pragma unroll
    for (int i = 0; i < 32; i += 8)
        tile[ty + i][tx] = qkv[(size_t)(b * 2048 + s0 + ty + i) * 3072 + 2048 + h * 64 + d0 + tx];
    __syncthreads();
#pragma unroll
    for (int i = 0; i < 32; i += 8)
        vt[((size_t)bh * 64 + d0 + ty + i) * 2048 + s0 + tx] = tile[tx][ty + i];
}

// ---------------------------------------------------------------------------
__global__ void concat3_k(const float* a, const float* b, const float* c, float* out)
{
    int i = blockIdx.x * 256 + threadIdx.x;
    if (i < 3072) out[i] = (i < 1024) ? a[i] : (i < 2048 ? b[i - 1024] : c[i - 2048]);
}

// ---------------------------------------------------------------------------
// mask dtype detection: 0 = int32 0/1, 1 = packed bytes, 2 = f32 0/1
// ---------------------------------------------------------------------------
__global__ __launch_bounds__(1024) void detect_mask_k(
    const unsigned int* __restrict__ m, int* __restrict__ flag)
{
    __shared__ int f1, f2;
    if (threadIdx.x == 0) { f1 = 0; f2 = 0; }
    __syncthreads();
    int l1 = 0, l2 = 0;
    for (int i = threadIdx.x; i < 16384; i += 1024) {
        unsigned v = m[i];
        l1 |= (v > 1u);
        l2 |= (v != 0u && v != 0x3f800000u);
    }
    if (l1) atomicOr(&f1, 1);
    if (l2) atomicOr(&f2, 1);
    __syncthreads();
    if (threadIdx.x == 0) {
        int mode = 0;
        if (f1) mode = f2 ? 1 : 2;
        *flag = mode;
    }
}

// ---------------------------------------------------------------------------
// bit-pack mask: packed[i>>6] bit (i&63) = keep(element i)
// ---------------------------------------------------------------------------
__global__ __launch_bounds__(256) void pack_mask_k(
    const void* __restrict__ mask, const int* __restrict__ flag,
    unsigned long long* __restrict__ packed, long long nelem)
{
    const int mode = *flag;
    const long long stride = (long long)gridDim.x * 256;
    long long i = (long long)blockIdx.x * 256 + threadIdx.x;
    if (mode == 0) {
        const int* m = (const int*)mask;
        for (; i < nelem; i += stride) {
            unsigned long long bl = __ballot(m[i] != 0);
            if ((threadIdx.x & 63) == 0) packed[i >> 6] = bl;
        }
    } else if (mode == 1) {
        const unsigned char* m = (const unsigned char*)mask;
        for (; i < nelem; i += stride) {
            unsigned long long bl = __ballot(m[i] != 0);
            if ((threadIdx.x & 63) == 0) packed[i >> 6] = bl;
        }
    } else {
        const float* m = (const float*)mask;
        for (; i < nelem; i += stride) {
            unsigned long long bl = __ballot(m[i] != 0.f);
            if ((threadIdx.x & 63) == 0) packed[i >> 6] = bl;
        }
    }
}

// ---------------------------------------------------------------------------
// 256x256 8-phase GEMM (T1+T2+T3+T4+T5): C(M,N) = A(M,K) @ Bt(N,K)^T + bias
// ---------------------------------------------------------------------------
template<int EPI>
__global__ __launch_bounds__(512) void gemm256_bt(
    const unsigned short* __restrict__ A, const unsigned short* __restrict__ Bt,
    const float* __restrict__ bias, void* __restrict__ Cout,
    int M, int N, int K)
{
    __shared__ __align__(16) unsigned short lds[2][2][256 * 64];
    const int t = threadIdx.x;
    const int lane = t & 63;
    const int wid = t >> 6;
    const int l16 = lane & 15, g = lane >> 4;
    const int wr = wid >> 2, wc = wid & 3;   // 2M x 4N wave grid

    const int nbx = gridDim.x, nwg = nbx * gridDim.y;
    const int orig = blockIdx.y * nbx + blockIdx.x;
    const int qq = nwg >> 3, rr = nwg & 7;
    const int xcd = orig & 7, idx = orig >> 3;
    const int wg = (xcd < rr) ? (xcd * (qq + 1) + idx)
                              : (rr * (qq + 1) + (xcd - rr) * qq + idx);
    const int bm = (wg / nbx) * 256, bn = (wg % nbx) * 256;

    const int ntiles = K >> 6;
    auto kof = [&](int s) { return (s < ntiles ? s : ntiles - 1) << 6; };

    auto stage_half = [&](const unsigned short* __restrict__ P, int grow0, int k0,
                          int buf, int ab, int half) {
#pragma unroll
        for (int rnd = 0; rnd < 2; ++rnd) {
            const int off = rnd * 8192 + t * 16;
            const int sw  = SWZ(off);
            const int row = off >> 7;
            const int col = (sw & 127) >> 1;
            gload16(&P[(size_t)(grow0 + half * 128 + row) * K + k0 + col],
                    &lds[buf][ab][half * 8192 + (off >> 1)]);
        }
    };

    auto lda = [&](int buf, int m, int kc) -> short8 {
        const int byte = ((m * 32 + wr * 16 + l16) * 64 + kc * 32 + g * 8) * 2;
        return *(const short8*)((const char*)&lds[buf][0][0] + SWZ(byte));
    };
    auto ldb = [&](int buf, int n, int kc) -> short8 {
        const int byte = ((n * 64 + wc * 16 + l16) * 64 + kc * 32 + g * 8) * 2;
        return *(const short8*)((const char*)&lds[buf][1][0] + SWZ(byte));
    };

    f32x4 acc[8][4] = {};
    short8 af[4][2];

    stage_half(A,  bm, 0,  0, 0, 0);
    stage_half(A,  bm, 0,  0, 0, 1);
    stage_half(Bt, bn, 0,  0, 1, 0);
    stage_half(Bt, bn, 0,  0, 1, 1);
    stage_half(A,  bm, 64, 1, 0, 0);
    stage_half(Bt, bn, 64, 1, 1, 0);
    asm volatile("s_waitcnt vmcnt(4)" ::: "memory");
    __builtin_amdgcn_s_barrier();

#define PH(buf, mh, nh, doLoadA, STAGE_STMT, doVM)                                  \
  {                                                                                  \
    if (doLoadA) {                                                                   \
      _Pragma("unroll") for (int mm = 0; mm < 4; ++mm)                               \
      _Pragma("unroll") for (int kc = 0; kc < 2; ++kc)                               \
        af[mm][kc] = lda(buf, (mh) * 4 + mm, kc);                                    \
    }                                                                                \
    short8 bf[2][2];                                                                 \
    _Pragma("unroll") for (int nn = 0; nn < 2; ++nn)                                 \
    _Pragma("unroll") for (int kc = 0; kc < 2; ++kc)                                 \
      bf[nn][kc] = ldb(buf, (nh) * 2 + nn, kc);                                      \
    STAGE_STMT;                                                                      \
    __builtin_amdgcn_s_barrier();                                                    \
    __builtin_amdgcn_s_setprio(1);                                                   \
    _Pragma("unroll") for (int mm = 0; mm < 4; ++mm)                                 \
    _Pragma("unroll") for (int nn = 0; nn < 2; ++nn)                                 \
    _Pragma("unroll") for (int kc = 0; kc < 2; ++kc)                                 \
      acc[(mh) * 4 + mm][(nh) * 2 + nn] = __builtin_amdgcn_mfma_f32_16x16x32_bf16(   \
          af[mm][kc], bf[nn][kc], acc[(mh) * 4 + mm][(nh) * 2 + nn], 0, 0, 0);       \
    __builtin_amdgcn_s_setprio(0);                                                   \
    if (doVM) { asm volatile("s_waitcnt vmcnt(4)" ::: "memory"); }                   \
    __builtin_amdgcn_s_barrier();                                                    \
  }

    const int half_ntiles = ntiles >> 1;
    for (int i = 0; i < half_ntiles; ++i) {
        const int k1 = (2 * i + 1) << 6;
        const int k2 = kof(2 * i + 2);
        const int k3 = kof(2 * i + 3);
        PH(0, 0, 0, 1, (stage_half(A,  bm, k1, 1, 0, 1)), 0)
        PH(0, 0, 1, 0, (stage_half(Bt, bn, k1, 1, 1, 1)), 0)
        PH(0, 1, 0, 1, (stage_half(A,  bm, k2, 0, 0, 0)), 0)
        PH(0, 1, 1, 0, (stage_half(Bt, bn, k2, 0, 1, 0)), 1)
        PH(1, 0, 0, 1, (stage_half(A,  bm, k2, 0, 0, 1)), 0)
        PH(1, 0, 1, 0, (stage_half(Bt, bn, k2, 0, 1, 1)), 0)
        PH(1, 1, 0, 1, (stage_half(A,  bm, k3, 1, 0, 0)), 0)
        PH(1, 1, 1, 0, (stage_half(Bt, bn, k3, 1, 1, 0)), 1)
    }
#undef PH

#pragma unroll
    for (int m = 0; m < 8; ++m) {
        const int row0 = bm + m * 32 + wr * 16 + g * 4;
#pragma unroll
        for (int n = 0; n < 4; ++n) {
            const int col = bn + n * 64 + wc * 16 + l16;
            const float bb = bias[col];
#pragma unroll
            for (int r = 0; r < 4; ++r) {
                float v = acc[m][n][r] + bb;
                if (EPI == 1) v = fmaxf(v, 0.f);
                ((unsigned short*)Cout)[(size_t)(row0 + r) * N + col] = f2bf(v);
            }
        }
    }
}

// ---------------------------------------------------------------------------
// 128x128 GEMM (m97 structure): used for Wo and FF2 (EPI 2: +resid, f32 out)
// ---------------------------------------------------------------------------
template<int EPI>
__global__ __launch_bounds__(256) void gemm_bt(
    const unsigned short* __restrict__ A, const unsigned short* __restrict__ Bt,
    const float* __restrict__ bias, const float* __restrict__ resid,
    void* __restrict__ Cout, int M, int N, int K)
{
    __shared__ unsigned short As[128 * 64];
    __shared__ unsigned short Bs[128 * 64];
    const int t = threadIdx.x;
    const int lane = t & 63, wid = t >> 6;
    const int l16 = lane & 15, g = lane >> 4;
    const int wr = wid >> 1, wc = wid & 1;
    const int bm = blockIdx.y * 128, bn = blockIdx.x * 128;

    f32x4 acc[4][4] = {};

    for (int k0 = 0; k0 < K; k0 += 64) {
        __syncthreads();
#pragma unroll
        for (int i = 0; i < 4; ++i) {
            int linear = i * 2048 + t * 8;
            int row = linear >> 6, col = linear & 63;
            gload16(&A[(size_t)(bm + row) * K + k0 + col], &As[linear]);
        }
#pragma unroll
        for (int i = 0; i < 4; ++i) {
            int linear = i * 2048 + t * 8;
            int row = linear >> 6, col = linear & 63;
            gload16(&Bt[(size_t)(bn + row) * K + k0 + col], &Bs[linear]);
        }
        __syncthreads();
#pragma unroll
        for (int kc = 0; kc < 2; ++kc) {
            short8 a[4], b[4];
#pragma unroll
            for (int m = 0; m < 4; ++m)
                a[m] = *(const short8*)&As[(wr * 64 + m * 16 + l16) * 64 + kc * 32 + g * 8];
#pragma unroll
            for (int n = 0; n < 4; ++n)
                b[n] = *(const short8*)&Bs[(wc * 64 + n * 16 + l16) * 64 + kc * 32 + g * 8];
#pragma unroll
            for (int m = 0; m < 4; ++m)
#pragma unroll
                for (int n = 0; n < 4; ++n)
                    acc[m][n] = __builtin_amdgcn_mfma_f32_16x16x32_bf16(a[m], b[n], acc[m][n], 0, 0, 0);
        }
    }

#pragma unroll
    for (int m = 0; m < 4; ++m) {
        const int row0 = bm + wr * 64 + m * 16 + g * 4;
#pragma unroll
        for (int n = 0; n < 4; ++n) {
            const int col = bn + wc * 64 + n * 16 + l16;
            const float bb = bias[col];
#pragma unroll
            for (int r = 0; r < 4; ++r) {
                float v = acc[m][n][r] + bb;
                const size_t idx = (size_t)(row0 + r) * N + col;
                if (EPI == 2) {
                    ((float*)Cout)[idx] = v + resid[idx];
                } else {
                    if (EPI == 1) v = fmaxf(v, 0.f);
                    ((unsigned short*)Cout)[idx] = f2bf(v);
                }
            }
        }
    }
}

// ---------------------------------------------------------------------------
// Flash attention R7: 8 waves / 128 q-rows per block; K and V^T tiles staged
// in LDS (XOR-swizzled, double-buffered, counted vmcnt(2)); packed mask;
// no-max softmax (P = keep ? exp(S/8) : 0, epilogue denom reduce).
// grid: (S/128, B*H). block: 512 thr = 8 waves; wave w owns 16 q-rows.
// ---------------------------------------------------------------------------
__global__ __launch_bounds__(512) void attn_k(
    const unsigned short* __restrict__ qkv,
    const unsigned short* __restrict__ vt,
    const unsigned long long* __restrict__ pmask,
    unsigned short* __restrict__ ctx)
{
    __shared__ __align__(16) unsigned short Ks[2][64 * 64];  // [kk][d], swizzled
    __shared__ __align__(16) unsigned short Vs[2][64 * 64];  // [d][kk], swizzled
    __shared__ unsigned short Pl[8][16 * 72];                // per-wave P [q][kk]
    const int t = threadIdx.x, lane = t & 63, w = t >> 6;
    const int l16 = lane & 15, g = lane >> 4;
    const int bh = blockIdx.y;
    const int b = bh >> 4, h = bh & 15;
    const int q0 = blockIdx.x * 128;

    // Q fragments: lane holds Q[q0 + w*16 + l16][g*8 + e (+32 for second chunk)]
    const size_t rowQ = (size_t)(b * 2048 + q0 + w * 16 + l16) * 3072 + h * 64;
    const short8 qf0 = *(const short8*)&qkv[rowQ + g * 8];
    const short8 qf1 = *(const short8*)&qkv[rowQ + 32 + g * 8];

    const unsigned long long* mbase =
        pmask + ((size_t)bh * 2048 + q0 + w * 16 + g * 4) * 32;

    // staging: one gload16 per thread per tile. dest linear; source column
    // pre-XOR-swizzled so a swizzled read returns the logical element.
    const int soff = t * 16;                 // byte offset in 8 KiB tile
    const int srow = soff >> 7;              // tile row 0..63
    const int scol = ((soff & 127) ^ ((srow & 7) << 4)) >> 1;   // source col (shorts)
    const size_t kRowBase = (size_t)(b * 2048) * 3072 + 1024 + h * 64;
    const unsigned short* vbase = &vt[(size_t)bh * 64 * 2048];

    auto stageK = [&](int buf, int kt) {
        gload16(&qkv[kRowBase + (size_t)(kt * 64 + srow) * 3072 + scol],
                &Ks[buf][soff >> 1]);
    };
    auto stageV = [&](int buf, int kt) {
        gload16(&vbase[(size_t)srow * 2048 + kt * 64 + scol],
                &Vs[buf][soff >> 1]);
    };
    // swizzled b128 read: logical (row r, byte-in-row X)
    auto ldK = [&](int buf, int r, int kc) -> short8 {
        const int byte = r * 128 + ((kc * 64 + g * 16) ^ ((r & 7) << 4));
        return *(const short8*)((const char*)Ks[buf] + byte);
    };
    auto ldV = [&](int buf, int r, int kc) -> short8 {
        const int byte = r * 128 + ((kc * 64 + g * 16) ^ ((r & 7) << 4));
        return *(const short8*)((const char*)Vs[buf] + byte);
    };

    f32x4 acc[4] = {};
    float lrow[4] = { 0.f, 0.f, 0.f, 0.f };

    // prologue: stage tile 0 into buf 0
    stageK(0, 0);
    stageV(0, 0);

    int buf = 0;
    for (int kt = 0; kt < 32; ++kt) {
        const int knext = (kt < 31) ? kt + 1 : 31;
        // issue next-tile staging into the other buffer (2 VMEM ops)
        stageK(buf ^ 1, knext);
        stageV(buf ^ 1, knext);
        // wait current tile landed (2 next-tile loads stay in flight)
        asm volatile("s_waitcnt vmcnt(2)" ::: "memory");
        __builtin_amdgcn_s_barrier();
        asm volatile("" ::: "memory");

        // mask words for this thread's 4 q-rows
        unsigned long long mw[4];
#pragma unroll
        for (int j = 0; j < 4; ++j) mw[j] = mbase[j * 32 + kt];

        // S = Q K^T from LDS
        f32x4 s[4] = {};
        __builtin_amdgcn_s_setprio(1);
#pragma unroll
        for (int n = 0; n < 4; ++n) {
            const short8 kf0 = ldK(buf, n * 16 + l16, 0);
            const short8 kf1 = ldK(buf, n * 16 + l16, 1);
            s[n] = __builtin_amdgcn_mfma_f32_16x16x32_bf16(qf0, kf0, s[n], 0, 0, 0);
            s[n] = __builtin_amdgcn_mfma_f32_16x16x32_bf16(qf1, kf1, s[n], 0, 0, 0);
        }
        __builtin_amdgcn_s_setprio(0);

        // P = keep ? exp(S/8) : 0 ; in-thread partial denominator
#pragma unroll
        for (int n = 0; n < 4; ++n) {
            const int sh = n * 16 + l16;
#pragma unroll
            for (int j = 0; j < 4; ++j) {
                const bool keep = (mw[j] >> sh) & 1ull;
                const float p = keep ? __expf(s[n][j] * 0.125f) : 0.f;
                s[n][j] = p;
                lrow[j] += p;
            }
        }

        // P -> bf16 -> per-wave LDS [q][kk] (wave-local, no barrier needed)
#pragma unroll
        for (int n = 0; n < 4; ++n)
#pragma unroll
            for (int j = 0; j < 4; ++j)
                Pl[w][(g * 4 + j) * 72 + n * 16 + l16] = f2bf(s[n][j]);

        // O += P V from LDS
        __builtin_amdgcn_s_setprio(1);
#pragma unroll
        for (int c = 0; c < 2; ++c) {
            const short8 pf = *(const short8*)&Pl[w][l16 * 72 + c * 32 + g * 8];
#pragma unroll
            for (int n = 0; n < 4; ++n) {
                const short8 vf = ldV(buf, n * 16 + l16, c);
                acc[n] = __builtin_amdgcn_mfma_f32_16x16x32_bf16(pf, vf, acc[n], 0, 0, 0);
            }
        }
        __builtin_amdgcn_s_setprio(0);

        // all waves done reading buf before it is overwritten next iteration
        asm volatile("" ::: "memory");
        __builtin_amdgcn_s_barrier();
        buf ^= 1;
    }

    // epilogue: complete denominator across the 16-lane group (once)
#pragma unroll
    for (int j = 0; j < 4; ++j) {
#pragma unroll
        for (int d = 1; d < 16; d <<= 1) lrow[j] += __shfl_xor(lrow[j], d);
        lrow[j] = 1.f / fmaxf(lrow[j], 1e-30f);
    }

#pragma unroll
    for (int n = 0; n < 4; ++n)
#pragma unroll
        for (int j = 0; j < 4; ++j) {
            const int q = q0 + w * 16 + g * 4 + j;
            ctx[(size_t)(b * 2048 + q) * 1024 + h * 64 + n * 16 + l16] = f2bf(acc[n][j] * lrow[j]);
        }
}

// ---------------------------------------------------------------------------
// row LayerNorm over 1024. WB=1: also write bf16 copy.
// ---------------------------------------------------------------------------
template<int WB>
__global__ __launch_bounds__(256) void ln_k(
    const float* __restrict__ in, const float* __restrict__ gw, const float* __restrict__ bw,
    float* __restrict__ outF, unsigned short* __restrict__ outB)
{
    __shared__ float red[2][4];
    const int row = blockIdx.x, t = threadIdx.x;
    const f32x4 v = *(const f32x4*)&in[(size_t)row * 1024 + t * 4];
    float s = v[0] + v[1] + v[2] + v[3];
    float ss = v[0] * v[0] + v[1] * v[1] + v[2] * v[2] + v[3] * v[3];
#pragma unroll
    for (int d = 1; d < 64; d <<= 1) { s += __shfl_xor(s, d); ss += __shfl_xor(ss, d); }
    if ((t & 63) == 0) { red[0][t >> 6] = s; red[1][t >> 6] = ss; }
    __syncthreads();
    s = red[0][0] + red[0][1] + red[0][2] + red[0][3];
    ss = red[1][0] + red[1][1] + red[1][2] + red[1][3];
    const float mu = s * (1.f / 1024.f);
    const float var = ss * (1.f / 1024.f) - mu * mu;
    const float rs = rsqrtf(var + 1e-5f);
    f32x4 y;
#pragma unroll
    for (int e = 0; e < 4; ++e)
        y[e] = (v[e] - mu) * rs * gw[t * 4 + e] + bw[t * 4 + e];
    *(f32x4*)&outF[(size_t)row * 1024 + t * 4] = y;
    if (WB) {
        u16x4 o = { f2bf(y[0]), f2bf(y[1]), f2bf(y[2]), f2bf(y[3]) };
        *(u16x4*)&outB[(size_t)row * 1024 + t * 4] = o;
    }
}

// ---------------------------------------------------------------------------
extern "C" void kernel_launch(void* const* d_in, const int* in_sizes, int n_in,
                              void* d_out, int out_size, void* d_ws, size_t ws_size,
                              hipStream_t stream)
{
    (void)n_in; (void)out_size; (void)ws_size;
    const float* x   = (const float*)d_in[0];
    const void*  mask = d_in[1];
    const float* Wq  = (const float*)d_in[2];
    const float* bq  = (const float*)d_in[3];
    const float* Wk  = (const float*)d_in[4];
    const float* bk  = (const float*)d_in[5];
    const float* Wv  = (const float*)d_in[6];
    const float* bv  = (const float*)d_in[7];
    const float* Wo  = (const float*)d_in[8];
    const float* bo  = (const float*)d_in[9];
    const float* g1  = (const float*)d_in[10];
    const float* be1 = (const float*)d_in[11];
    const float* g2  = (const float*)d_in[12];
    const float* be2 = (const float*)d_in[13];
    const float* W1  = (const float*)d_in[14];
    const float* b1  = (const float*)d_in[15];
    const float* W2  = (const float*)d_in[16];
    const float* b2  = (const float*)d_in[17];

    const int M = 4096;   // B*S
    const long long maskN = in_sizes[1];

    char* wsb = (char*)d_ws;
    size_t off = 0;
    auto alloc = [&](size_t bytes) -> char* {
        char* p = wsb + off;
        off += (bytes + 255) & ~(size_t)255;
        return p;
    };
    int*            flag   = (int*)           alloc(256);
    unsigned long long* pm = (unsigned long long*)alloc((size_t)(maskN / 64) * 8);
    unsigned short* xb     = (unsigned short*)alloc((size_t)M * 1024 * 2);
    unsigned short* wqkvT  = (unsigned short*)alloc((size_t)3072 * 1024 * 2);
    unsigned short* woT    = (unsigned short*)alloc((size_t)1024 * 1024 * 2);
    unsigned short* w1T    = (unsigned short*)alloc((size_t)4096 * 1024 * 2);
    unsigned short* w2T    = (unsigned short*)alloc((size_t)1024 * 4096 * 2);
    float*          bqkv   = (float*)         alloc(3072 * 4);
    unsigned short* qkv    = (unsigned short*)alloc((size_t)M * 3072 * 2);
    unsigned short* vtb    = (unsigned short*)alloc((size_t)32 * 64 * 2048 * 2);
    unsigned short* ctxb   = (unsigned short*)alloc((size_t)M * 1024 * 2);
    float*          r1f    = (float*)         alloc((size_t)M * 1024 * 4);
    float*          x1f    = (float*)         alloc((size_t)M * 1024 * 4);
    unsigned short* x1b    = (unsigned short*)alloc((size_t)M * 1024 * 2);
    unsigned short* hb     = (unsigned short*)alloc((size_t)M * 4096 * 2);

    detect_mask_k<<<1, 1024, 0, stream>>>((const unsigned int*)mask, flag);
    pack_mask_k<<<2048, 256, 0, stream>>>(mask, flag, pm, maskN);
    f32_to_bf16_k<<<4096, 256, 0, stream>>>(x, xb, M * 1024 / 4);
    transpose_k<<<dim3(32, 32),  256, 0, stream>>>(Wq, wqkvT,                1024, 1024);
    transpose_k<<<dim3(32, 32),  256, 0, stream>>>(Wk, wqkvT + 1024 * 1024,  1024, 1024);
    transpose_k<<<dim3(32, 32),  256, 0, stream>>>(Wv, wqkvT + 2048 * 1024,  1024, 1024);
    transpose_k<<<dim3(32, 32),  256, 0, stream>>>(Wo, woT,                  1024, 1024);
    transpose_k<<<dim3(128, 32), 256, 0, stream>>>(W1, w1T, 1024, 4096);
    transpose_k<<<dim3(32, 128), 256, 0, stream>>>(W2, w2T, 4096, 1024);
    concat3_k<<<12, 256, 0, stream>>>(bq, bk, bv, bqkv);

    // QKV projection: 8-phase 256^2 (192 blocks)
    gemm256_bt<0><<<dim3(12, 16), 512, 0, stream>>>(xb, wqkvT, bqkv, qkv, M, 3072, 1024);
    // per-head V^T
    vtrans_k<<<dim3(64, 2, 32), 256, 0, stream>>>(qkv, vtb);
    // attention (8-wave, LDS-staged K/V) -> ctx bf16
    attn_k<<<dim3(16, 32), 512, 0, stream>>>(qkv, vtb, pm, ctxb);
    // attn_out + residual: r1 = ctx@Wo + bo + x  (f32)
    gemm_bt<2><<<dim3(8, 32), 256, 0, stream>>>(ctxb, woT, bo, x, r1f, M, 1024, 1024);
    // LN1 -> x1 (f32 + bf16)
    ln_k<1><<<4096, 256, 0, stream>>>(r1f, g1, be1, x1f, x1b);
    // FF1: relu(x1@W1 + b1) -> hb bf16 : 8-phase 256^2 (256 blocks)
    gemm256_bt<1><<<dim3(16, 16), 512, 0, stream>>>(x1b, w1T, b1, hb, M, 4096, 1024);
    // FF2 + residual: r1 = hb@W2 + b2 + x1  (f32)
    gemm_bt<2><<<dim3(8, 32), 256, 0, stream>>>(hb, w2T, b2, x1f, r1f, M, 1024, 4096);
    // LN2 -> out
    ln_k<0><<<4096, 256, 0, stream>>>(r1f, g2, be2, (float*)d_out, nullptr);
}